// Round 8
// baseline (538.835 us; speedup 1.0000x reference)
//
#include <hip/hip_runtime.h>
#include <math.h>

// ---- problem constants ----
#define NPATCH 16384          // B * T / P
#define SEQ    512            // T / P
#define LOSS_OFF 16777216
#define IDX_OFF  16777217

typedef short bf8 __attribute__((ext_vector_type(8)));    // 8 bf16 (4 VGPRs)
typedef _Float16 h8 __attribute__((ext_vector_type(8)));  // 8 f16 (4 VGPRs)
typedef float f32x4 __attribute__((ext_vector_type(4)));  // MFMA acc

__device__ inline short f2bf(float x) {          // fp32 -> bf16 RNE
  unsigned u = __float_as_uint(x);
  u += 0x7fffu + ((u >> 16) & 1u);
  return (short)(u >> 16);
}
__device__ inline float bf2f(short h) {
  return __uint_as_float(((unsigned)(unsigned short)h) << 16);
}

// f16 split with 4096-scaled lo plane (encoder + VQ only).  hi forced to 0
// below f16-normal; VQ operands pre-scaled by pow2 so clamp never fires (R5).
__device__ inline void splitf16(float v, short& hi, short& lo) {
  _Float16 h = (fabsf(v) < 6.1035156e-5f) ? (_Float16)0.f : (_Float16)v;
  hi = __builtin_bit_cast(short, h);
  lo = __builtin_bit_cast(short, (_Float16)((v - (float)h) * 4096.f));
}

// encoder weight plane offsets (in halfs) inside ewh/ewl
#define EW2_OFF 0        // [t][co][ci]  4*64*32  = 8192
#define EW3_OFF 8192     // [t][co][ci]  3*64*64  = 12288
#define ERA_OFF 20480    // [rl][t][co][ci] 2*3*32*64 = 12288
#define ERB_OFF 32768    // [rl][co][ci] 2*64*32  = 4096
#define EPW_OFF 36864    // [co][ci]     32*64    = 2048
#define EWTOT   38912

// ---- pre-split + transpose encoder weights into f16 hi / scaled-lo planes ----
__global__ __launch_bounds__(256) void enc_split(
    const float* __restrict__ w2, const float* __restrict__ w3,
    const float* __restrict__ rw1, const float* __restrict__ rw2,
    const float* __restrict__ pw,
    unsigned short* __restrict__ eh, unsigned short* __restrict__ el) {
  int i = blockIdx.x * 256 + threadIdx.x;     // 0..38911 exactly
  float v;
  if (i < 8192) {                 // EW2 [t][co][ci] <- w2[co][ci][t]
    int t = i >> 11, co = (i >> 5) & 63, ci = i & 31;
    v = w2[(co * 32 + ci) * 4 + t];
  } else if (i < 20480) {         // EW3 [t][co][ci] <- w3[co][ci][t]
    int j = i - 8192;
    int t = j >> 12, co = (j >> 6) & 63, ci = j & 63;
    v = w3[(co * 64 + ci) * 3 + t];
  } else if (i < 32768) {         // ERA [rl][t][co][ci] <- rw1[rl][co][ci][t]
    int j = i - 20480;
    int rl = j / 6144; j -= rl * 6144;
    int t = j >> 11, co = (j >> 6) & 31, ci = j & 63;
    v = rw1[((rl * 32 + co) * 64 + ci) * 3 + t];
  } else if (i < 36864) {         // ERB [rl][co][ci] <- rw2
    int j = i - 32768;
    int rl = j >> 11, co = (j >> 5) & 63, ci = j & 31;
    v = rw2[(rl * 64 + co) * 32 + ci];
  } else {                        // EPW [co][ci] <- pw
    int j = i - 36864;
    int co = j >> 6, ci = j & 63;
    v = pw[co * 64 + ci];
  }
  short hh_, ll_;
  splitf16(v, hh_, ll_);
  eh[i] = (unsigned short)hh_;
  el[i] = (unsigned short)ll_;
}

// ---- codebook split (x64 pre-scale) + fp32 |c|^2 ----
__global__ __launch_bounds__(256) void cb_split(
    const float* __restrict__ cb, unsigned short* __restrict__ ch,
    unsigned short* __restrict__ cl, float* __restrict__ cn) {
  const int i = blockIdx.x * 256 + threadIdx.x;   // 0..131071 exactly (512 blocks)
  float v = cb[i];
  short hi, lo;
  splitf16(v * 64.f, hi, lo);                     // c*64: f16-normal
  ch[i] = (unsigned short)hi;
  cl[i] = (unsigned short)lo;
  float s = v * v;                                // row = i>>7 (2 rows/block)
#pragma unroll
  for (int o = 1; o < 64; o <<= 1) s += __shfl_xor(s, o);
  __shared__ float red[4];
  if ((threadIdx.x & 63) == 0) red[threadIdx.x >> 6] = s;
  __syncthreads();
  if (threadIdx.x == 0)   cn[i >> 7] = red[0] + red[1];
  if (threadIdx.x == 128) cn[i >> 7] = red[2] + red[3];
}

// ====== encoder v7 (proven 73us config) + z hi/lo plane writes (x256 scale) ======
#define H1P 2624   // 8 patches * 328
#define H2P 2304   // 32 rows * 72
__global__ __launch_bounds__(256, 4) void encoder7(
    const float* __restrict__ x,
    const float* __restrict__ w1, const float* __restrict__ b1,
    const float* __restrict__ b2, const float* __restrict__ b3,
    const float* __restrict__ rb1, const float* __restrict__ rb2,
    const float* __restrict__ pb,
    const unsigned short* __restrict__ ewh, const unsigned short* __restrict__ ewl,
    float* __restrict__ z, unsigned short* __restrict__ zh,
    unsigned short* __restrict__ zl) {
  __shared__ __align__(16) short arena[9856];   // 19712 B
  short* H1h = arena;                  // [8 pat][8 pos][32 ch], pos stride 40
  short* H1l = arena + H1P;
  short* H2h = arena + 2 * H1P;        // [32 m][64 ch], stride 72
  short* H2l = arena + 2 * H1P + H2P;
  short* T1h = arena;                  // [32 m][32 ch], stride 40 (H1 dead)
  short* T1l = arena + 1280;
  float* XS  = (float*)(arena + 2 * H1P);  // [8][16] f32 (H2h head, dead pre-conv2)

  const int tid = threadIdx.x;
  const int wave = tid >> 6, lane = tid & 63, quad = lane >> 4, l15 = lane & 15;
  const int mt = wave >> 1, nh = wave & 1;     // m-tile, nt-half
  const size_t pbase = (size_t)blockIdx.x * 8;
  const h8 zh8 = {0, 0, 0, 0, 0, 0, 0, 0};
  const f32x4 zf4 = {0.f, 0.f, 0.f, 0.f};

  h8 w2h[4][2], w2l[4][2];
#pragma unroll
  for (int t = 0; t < 4; ++t)
#pragma unroll
    for (int j = 0; j < 2; ++j) {
      const int wb = EW2_OFF + (t * 64 + (nh * 2 + j) * 16 + l15) * 32 + quad * 8;
      w2h[t][j] = *reinterpret_cast<const h8*>(ewh + wb);
      w2l[t][j] = *reinterpret_cast<const h8*>(ewl + wb);
    }

  if (tid < 32) {
    int pp = tid >> 2, i = (tid & 3) * 4;
    *reinterpret_cast<float4*>(&XS[pp * 16 + i]) =
        *reinterpret_cast<const float4*>(x + (pbase + pp) * 16 + i);
  }
  __syncthreads();

  { // ---- conv1 (VALU fp32) ----
    const int pp = tid >> 5, op = (tid >> 2) & 7, qt = tid & 3;
    float xv[4];
#pragma unroll
    for (int kk = 0; kk < 4; ++kk) {
      int ip = 2 * op + kk - 1;
      xv[kk] = (ip >= 0 && ip < 16) ? XS[pp * 16 + ip] : 0.f;
    }
    bf8 sh, sl;
#pragma unroll
    for (int c = 0; c < 8; ++c) {
      int co = qt * 8 + c;
      float4 wv = *reinterpret_cast<const float4*>(w1 + co * 4);
      float a = b1[co] + xv[0] * wv.x + xv[1] * wv.y + xv[2] * wv.z + xv[3] * wv.w;
      a = fmaxf(a, 0.f);
      short hs, ls;
      splitf16(a, hs, ls);
      sh[c] = hs; sl[c] = ls;
    }
    const int off = pp * 328 + op * 40 + qt * 8;
    *reinterpret_cast<bf8*>(&H1h[off]) = sh;
    *reinterpret_cast<bf8*>(&H1l[off]) = sl;
  }
  __syncthreads();

  f32x4 h3keep[2];

  // ---- conv2 ----
  f32x4 acc2A[2] = {zf4, zf4};
  f32x4 acc2B[2] = {zf4, zf4};
  {
    const float bs2_0 = b2[nh * 32 + l15];
    const float bs2_1 = b2[nh * 32 + 16 + l15];
    const int patch = mt * 4 + (l15 >> 2), outp = l15 & 3;
#pragma unroll
    for (int t = 0; t < 4; ++t) {
      const int ip = 2 * outp + t - 1;
      const bool vld = (unsigned)ip < 8u;
      const int aoff = patch * 328 + (vld ? ip : 0) * 40 + quad * 8;
      h8 ah = *reinterpret_cast<const h8*>(&H1h[aoff]);
      h8 al = *reinterpret_cast<const h8*>(&H1l[aoff]);
      if (!vld) { ah = zh8; al = zh8; }
#pragma unroll
      for (int j = 0; j < 2; ++j) {
        acc2A[j] = __builtin_amdgcn_mfma_f32_16x16x32_f16(ah, w2h[t][j], acc2A[j], 0, 0, 0);
        acc2B[j] = __builtin_amdgcn_mfma_f32_16x16x32_f16(ah, w2l[t][j], acc2B[j], 0, 0, 0);
        acc2B[j] = __builtin_amdgcn_mfma_f32_16x16x32_f16(al, w2h[t][j], acc2B[j], 0, 0, 0);
      }
    }
    h8 w3h[3][2][2], w3l[3][2][2];       // [t][ks][j]
#pragma unroll
    for (int t = 0; t < 3; ++t)
#pragma unroll
      for (int ks = 0; ks < 2; ++ks)
#pragma unroll
        for (int j = 0; j < 2; ++j) {
          const int wb = EW3_OFF + (t * 64 + (nh * 2 + j) * 16 + l15) * 64 + ks * 32 + quad * 8;
          w3h[t][ks][j] = *reinterpret_cast<const h8*>(ewh + wb);
          w3l[t][ks][j] = *reinterpret_cast<const h8*>(ewl + wb);
        }
#pragma unroll
    for (int j = 0; j < 2; ++j) {
      const int col = (nh * 2 + j) * 16 + l15;
      const float bs = (j == 0) ? bs2_0 : bs2_1;
#pragma unroll
      for (int r = 0; r < 4; ++r) {
        float v = fmaxf(acc2A[j][r] + acc2B[j][r] * (1.f / 4096.f) + bs, 0.f);
        short vh, vl;
        splitf16(v, vh, vl);
        const int m = mt * 16 + quad * 4 + r;
        H2h[m * 72 + col] = vh;
        H2l[m * 72 + col] = vl;
      }
    }
    __syncthreads();

    // ---- conv3 ----
    f32x4 accA[2] = {zf4, zf4};
    f32x4 accB[2] = {zf4, zf4};
    const float bs3_0 = b3[nh * 32 + l15];
    const float bs3_1 = b3[nh * 32 + 16 + l15];
    const int pos = l15 & 3;
#pragma unroll
    for (int t = 0; t < 3; ++t) {
      const int ip = pos + t - 1;
      const bool vld = (unsigned)ip < 4u;
      const int row = patch * 4 + (vld ? ip : 0);
#pragma unroll
      for (int ks = 0; ks < 2; ++ks) {
        const int aoff = row * 72 + ks * 32 + quad * 8;
        h8 ah = *reinterpret_cast<const h8*>(&H2h[aoff]);
        h8 al = *reinterpret_cast<const h8*>(&H2l[aoff]);
        if (!vld) { ah = zh8; al = zh8; }
#pragma unroll
        for (int j = 0; j < 2; ++j) {
          accA[j] = __builtin_amdgcn_mfma_f32_16x16x32_f16(ah, w3h[t][ks][j], accA[j], 0, 0, 0);
          accB[j] = __builtin_amdgcn_mfma_f32_16x16x32_f16(ah, w3l[t][ks][j], accB[j], 0, 0, 0);
          accB[j] = __builtin_amdgcn_mfma_f32_16x16x32_f16(al, w3h[t][ks][j], accB[j], 0, 0, 0);
        }
      }
    }
    __syncthreads();
#pragma unroll
    for (int j = 0; j < 2; ++j) {
      const int col = (nh * 2 + j) * 16 + l15;
      const float bs = (j == 0) ? bs3_0 : bs3_1;
#pragma unroll
      for (int r = 0; r < 4; ++r) {
        float v = accA[j][r] + accB[j][r] * (1.f / 4096.f) + bs;
        h3keep[j][r] = v;
        short vh, vl;
        splitf16(fmaxf(v, 0.f), vh, vl);
        const int m = mt * 16 + quad * 4 + r;
        H2h[m * 72 + col] = vh;
        H2l[m * 72 + col] = vl;
      }
    }
  }
  __syncthreads();

  for (int rl = 0; rl < 2; ++rl) {
    { // ---- res stage a ----
      h8 wah[3][2], wal[3][2];
#pragma unroll
      for (int t = 0; t < 3; ++t)
#pragma unroll
        for (int ks = 0; ks < 2; ++ks) {
          const int wb = ERA_OFF + ((rl * 3 + t) * 32 + nh * 16 + l15) * 64 + ks * 32 + quad * 8;
          wah[t][ks] = *reinterpret_cast<const h8*>(ewh + wb);
          wal[t][ks] = *reinterpret_cast<const h8*>(ewl + wb);
        }
      const float bsa = rb1[rl * 32 + nh * 16 + l15];
      f32x4 accA = zf4, accB = zf4;
      const int patch = mt * 4 + (l15 >> 2), pos = l15 & 3;
#pragma unroll
      for (int t = 0; t < 3; ++t) {
        const int ip = pos + t - 1;
        const bool vld = (unsigned)ip < 4u;
        const int row = patch * 4 + (vld ? ip : 0);
#pragma unroll
        for (int ks = 0; ks < 2; ++ks) {
          const int aoff = row * 72 + ks * 32 + quad * 8;
          h8 ah = *reinterpret_cast<const h8*>(&H2h[aoff]);
          h8 al = *reinterpret_cast<const h8*>(&H2l[aoff]);
          if (!vld) { ah = zh8; al = zh8; }
          accA = __builtin_amdgcn_mfma_f32_16x16x32_f16(ah, wah[t][ks], accA, 0, 0, 0);
          accB = __builtin_amdgcn_mfma_f32_16x16x32_f16(ah, wal[t][ks], accB, 0, 0, 0);
          accB = __builtin_amdgcn_mfma_f32_16x16x32_f16(al, wah[t][ks], accB, 0, 0, 0);
        }
      }
      const int col = nh * 16 + l15;
#pragma unroll
      for (int r = 0; r < 4; ++r) {
        float v = fmaxf(accA[r] + accB[r] * (1.f / 4096.f) + bsa, 0.f);
        short vh, vl;
        splitf16(v, vh, vl);
        const int m = mt * 16 + quad * 4 + r;
        T1h[m * 40 + col] = vh;
        T1l[m * 40 + col] = vl;
      }
    }
    __syncthreads();
    { // ---- res stage b ----
      h8 wbh[2], wbl[2];
#pragma unroll
      for (int j = 0; j < 2; ++j) {
        const int wb = ERB_OFF + (rl * 64 + (nh * 2 + j) * 16 + l15) * 32 + quad * 8;
        wbh[j] = *reinterpret_cast<const h8*>(ewh + wb);
        wbl[j] = *reinterpret_cast<const h8*>(ewl + wb);
      }
      const float bsb0 = rb2[rl * 64 + nh * 32 + l15];
      const float bsb1 = rb2[rl * 64 + nh * 32 + 16 + l15];
      f32x4 accA[2] = {zf4, zf4};
      f32x4 accB[2] = {zf4, zf4};
      const int aoff = (mt * 16 + l15) * 40 + quad * 8;
      h8 ah = *reinterpret_cast<const h8*>(&T1h[aoff]);
      h8 al = *reinterpret_cast<const h8*>(&T1l[aoff]);
#pragma unroll
      for (int j = 0; j < 2; ++j) {
        accA[j] = __builtin_amdgcn_mfma_f32_16x16x32_f16(ah, wbh[j], accA[j], 0, 0, 0);
        accB[j] = __builtin_amdgcn_mfma_f32_16x16x32_f16(ah, wbl[j], accB[j], 0, 0, 0);
        accB[j] = __builtin_amdgcn_mfma_f32_16x16x32_f16(al, wbh[j], accB[j], 0, 0, 0);
      }
#pragma unroll
      for (int j = 0; j < 2; ++j) {
        const int col = (nh * 2 + j) * 16 + l15;
        const float bs = (j == 0) ? bsb0 : bsb1;
#pragma unroll
        for (int r = 0; r < 4; ++r) {
          float v = h3keep[j][r] + accA[j][r] + accB[j][r] * (1.f / 4096.f) + bs;
          h3keep[j][r] = v;
          short vh, vl;
          splitf16(fmaxf(v, 0.f), vh, vl);
          const int m = mt * 16 + quad * 4 + r;
          H2h[m * 72 + col] = vh;
          H2l[m * 72 + col] = vl;
        }
      }
    }
    __syncthreads();
  }

  { // ---- pre 1x1 -> z (fp32) + z planes (x256 scale for VQ) ----
    h8 wph[2], wpl[2];
#pragma unroll
    for (int ks = 0; ks < 2; ++ks) {
      const int wb = EPW_OFF + (nh * 16 + l15) * 64 + ks * 32 + quad * 8;
      wph[ks] = *reinterpret_cast<const h8*>(ewh + wb);
      wpl[ks] = *reinterpret_cast<const h8*>(ewl + wb);
    }
    const float bs = pb[nh * 16 + l15];
    f32x4 accA = zf4, accB = zf4;
    const int arow = mt * 16 + l15;
#pragma unroll
    for (int ks = 0; ks < 2; ++ks) {
      const int aoff = arow * 72 + ks * 32 + quad * 8;
      h8 ah = *reinterpret_cast<const h8*>(&H2h[aoff]);
      h8 al = *reinterpret_cast<const h8*>(&H2l[aoff]);
      accA = __builtin_amdgcn_mfma_f32_16x16x32_f16(ah, wph[ks], accA, 0, 0, 0);
      accB = __builtin_amdgcn_mfma_f32_16x16x32_f16(ah, wpl[ks], accB, 0, 0, 0);
      accB = __builtin_amdgcn_mfma_f32_16x16x32_f16(al, wph[ks], accB, 0, 0, 0);
    }
    const int pn = mt * 4 + quad;
    const int col = nh * 16 + l15;
    float ov[4];
#pragma unroll
    for (int r = 0; r < 4; ++r) ov[r] = accA[r] + accB[r] * (1.f / 4096.f) + bs;
    const size_t off = (pbase + pn) * 128 + col * 4;
    *reinterpret_cast<float4*>(z + off) = *reinterpret_cast<float4*>(ov);
    ushort4 h4, l4;
    unsigned short* hp = (unsigned short*)&h4;
    unsigned short* lp = (unsigned short*)&l4;
#pragma unroll
    for (int r = 0; r < 4; ++r) {
      short vh, vl;
      splitf16(ov[r] * 256.f, vh, vl);    // z*256: f16-normal
      hp[r] = (unsigned short)vh;
      lp[r] = (unsigned short)vl;
    }
    *reinterpret_cast<ushort4*>(&zh[off]) = h4;
    *reinterpret_cast<ushort4*>(&zl[off]) = l4;
  }
}

// ======= transformer weight cast: fp32 -> single bf16 plane (once/launch) =======
__global__ __launch_bounds__(256) void cast_w(
    const float* __restrict__ qkv_w, const float* __restrict__ proj_w,
    const float* __restrict__ f1, const float* __restrict__ f2,
    const float* __restrict__ hw, unsigned short* __restrict__ wb) {
  int i = blockIdx.x * 256 + threadIdx.x;
  float v;
  if (i < 196608) v = qkv_w[i];
  else if (i < 262144) v = proj_w[i - 196608];
  else if (i < 393216) v = f1[i - 262144];
  else if (i < 524288) v = f2[i - 393216];
  else v = hw[i - 524288];
  wb[i] = (unsigned short)f2bf(v);
}

// ====== VQ argmin v3: split-f16 MFMA GEMM z.cb^T + |c|^2 + fused argmin ======
// Planes carry z*256 and c*64 -> acc = 2^14 * z.c; s = acc/16384 (exact pow2).
__global__ __launch_bounds__(256) void vq_argmin3(
    const unsigned short* __restrict__ Ahg, const unsigned short* __restrict__ Alg,
    const unsigned short* __restrict__ Bhg, const unsigned short* __restrict__ Blg,
    const float* __restrict__ cbf, unsigned long long* __restrict__ keys) {
  __shared__ short Ah[128 * 40], Al[128 * 40], Bh[64 * 40], Bl[64 * 40];
  __shared__ float cns[64];
  const int tid = threadIdx.x;
  const int n0 = blockIdx.x * 64, m0 = blockIdx.y * 128;
  const int wave = tid >> 6, lane = tid & 63, quad = lane >> 4, l15 = lane & 15;
  const f32x4 z4 = {0.f, 0.f, 0.f, 0.f};
  f32x4 accA[2][4], accB[2][4];
#pragma unroll
  for (int i = 0; i < 2; ++i)
#pragma unroll
    for (int j = 0; j < 4; ++j) { accA[i][j] = z4; accB[i][j] = z4; }
  { // |c|^2 for the block's 64 cols (fp32)
    const int lr = tid >> 2, q = tid & 3;
    const float4* bp = reinterpret_cast<const float4*>(cbf + (size_t)(n0 + lr) * 128 + q * 32);
    float s = 0.f;
#pragma unroll
    for (int e = 0; e < 8; ++e) {
      float4 v = bp[e];
      s += v.x * v.x + v.y * v.y + v.z * v.z + v.w * v.w;
    }
    s += __shfl_xor(s, 1); s += __shfl_xor(s, 2);
    if (q == 0) cns[lr] = s;
  }
  const int ra = tid >> 1, ha = (tid & 1) * 16;         // A: 128 rows, 16 shorts each
  const int rb = tid >> 2, hb = (tid & 3) * 8;          // B: 64 rows, 8 shorts each
  for (int k0 = 0; k0 < 128; k0 += 32) {
    {
      const size_t abase = (size_t)(m0 + ra) * 128 + k0 + ha;
      *reinterpret_cast<bf8*>(&Ah[ra * 40 + ha])     = *reinterpret_cast<const bf8*>(&Ahg[abase]);
      *reinterpret_cast<bf8*>(&Ah[ra * 40 + ha + 8]) = *reinterpret_cast<const bf8*>(&Ahg[abase + 8]);
      *reinterpret_cast<bf8*>(&Al[ra * 40 + ha])     = *reinterpret_cast<const bf8*>(&Alg[abase]);
      *reinterpret_cast<bf8*>(&Al[ra * 40 + ha + 8]) = *reinterpret_cast<const bf8*>(&Alg[abase + 8]);
      const size_t bbase = (size_t)(n0 + rb) * 128 + k0 + hb;
      *reinterpret_cast<bf8*>(&Bh[rb * 40 + hb]) = *reinterpret_cast<const bf8*>(&Bhg[bbase]);
      *reinterpret_cast<bf8*>(&Bl[rb * 40 + hb]) = *reinterpret_cast<const bf8*>(&Blg[bbase]);
    }
    __syncthreads();
    h8 af[2], afl[2], bfh[4], bfl[4];
#pragma unroll
    for (int mt = 0; mt < 2; ++mt) {
      int row = wave * 32 + mt * 16 + l15;
      af[mt]  = *reinterpret_cast<const h8*>(&Ah[row * 40 + quad * 8]);
      afl[mt] = *reinterpret_cast<const h8*>(&Al[row * 40 + quad * 8]);
    }
#pragma unroll
    for (int nt = 0; nt < 4; ++nt) {
      int row = nt * 16 + l15;
      bfh[nt] = *reinterpret_cast<const h8*>(&Bh[row * 40 + quad * 8]);
      bfl[nt] = *reinterpret_cast<const h8*>(&Bl[row * 40 + quad * 8]);
    }
#pragma unroll
    for (int nt = 0; nt < 4; ++nt)
#pragma unroll
      for (int mt = 0; mt < 2; ++mt) {
        accA[mt][nt] = __builtin_amdgcn_mfma_f32_16x16x32_f16(af[mt], bfh[nt], accA[mt][nt], 0, 0, 0);
        accB[mt][nt] = __builtin_amdgcn_mfma_f32_16x16x32_f16(af[mt], bfl[nt], accB[mt][nt], 0, 0, 0);
        accB[mt][nt] = __builtin_amdgcn_mfma_f32_16x16x32_f16(afl[mt], bfh[nt], accB[mt][nt], 0, 0, 0);
      }
    __syncthreads();
  }
#pragma unroll
  for (int mt = 0; mt < 2; ++mt)
#pragma unroll
    for (int r = 0; r < 4; ++r) {
      const int row = m0 + wave * 32 + mt * 16 + quad * 4 + r;
      unsigned long long key = ~0ull;
#pragma unroll
      for (int nt = 0; nt < 4; ++nt) {
        const int c16 = nt * 16 + l15;
        float s = (accA[mt][nt][r] + accB[mt][nt][r] * (1.f / 4096.f)) * (1.f / 16384.f);
        float dv = cns[c16] - 2.f * s;            // |c|^2 - 2 z.c
        unsigned u = __float_as_uint(dv);
        u = (u & 0x80000000u) ? ~u : (u | 0x80000000u);  // order-preserving
        unsigned long long k = ((unsigned long long)u << 32) | (unsigned)(n0 + c16);
        key = k < key ? k : key;
      }
#pragma unroll
      for (int off = 1; off < 16; off <<= 1) {
        unsigned long long o = __shfl_xor(key, off);
        key = o < key ? o : key;
      }
      if (l15 == 0) atomicMin(&keys[row], key);
    }
}

// ===== VQ part 3: gather q, loss partials, hh = q + pos (fp32 + bf16 plane) =====
__global__ __launch_bounds__(256) void vq_gather3(
    const float* __restrict__ z, const float* __restrict__ cb,
    const float* __restrict__ pos, const unsigned long long* __restrict__ keys,
    float* __restrict__ hh, unsigned short* __restrict__ hh_b,
    float* __restrict__ lpart, float* __restrict__ idx_out) {
  const int blk = blockIdx.x, tid = threadIdx.x;
  __shared__ int sidx[8];
  if (tid < 8) {
    unsigned long long k = keys[blk * 8 + tid];
    int id = (int)(unsigned)(k & 0xffffffffull);
    sidx[tid] = id;
    idx_out[blk * 8 + tid] = (float)id;
  }
  __syncthreads();
  const int p = tid >> 5, d = tid & 31;
  const size_t n = (size_t)blk * 8 + p;
  const int idx = sidx[p];
  float4 q = *reinterpret_cast<const float4*>(cb + (size_t)idx * 128 + d * 4);
  float4 zv = *reinterpret_cast<const float4*>(z + n * 128 + d * 4);
  float4 pv = *reinterpret_cast<const float4*>(pos + (size_t)(n & 511) * 128 + d * 4);
  float hv[4] = {q.x + pv.x, q.y + pv.y, q.z + pv.z, q.w + pv.w};
  *reinterpret_cast<float4*>(hh + n * 128 + d * 4) = *reinterpret_cast<float4*>(hv);
  ushort4 h4;
  unsigned short* hp = (unsigned short*)&h4;
#pragma unroll
  for (int e = 0; e < 4; ++e) hp[e] = (unsigned short)f2bf(hv[e]);
  *reinterpret_cast<ushort4*>(&hh_b[n * 128 + d * 4]) = h4;
  float dx = q.x - zv.x, dy = q.y - zv.y, dz = q.z - zv.z, dw = q.w - zv.w;
  float part = dx * dx + dy * dy + dz * dz + dw * dw;
#pragma unroll
  for (int o = 1; o < 64; o <<= 1) part += __shfl_xor(part, o);
  __shared__ float lred[4];
  if ((tid & 63) == 0) lred[tid >> 6] = part;
  __syncthreads();
  if (tid == 0) lpart[blk] = lred[0] + lred[1] + lred[2] + lred[3];
}

// ====== plain-bf16 MFMA GEMM v2: tile 64(M) x 64(N) — TLP-first ======
// grid (N/64, M/64).  ACT: 0=none 1=gelu.  SPLIT: 1 -> bf16 out, 0 -> fp32.
// Per-output MFMA accumulation order identical to mgemm_b (bit-identical C).
template <int ACT, int SPLIT>
__global__ __launch_bounds__(256) void mgemm_b64(
    const unsigned short* __restrict__ Ag, const unsigned short* __restrict__ Bg,
    const float* __restrict__ bias, float* __restrict__ C,
    unsigned short* __restrict__ Cb, int N) {
  __shared__ short Ah[64 * 40], Bh[64 * 40];
  const int tid = threadIdx.x;
  const int n0 = blockIdx.x * 64, m0 = blockIdx.y * 64;
  const int wave = tid >> 6, lane = tid & 63, quad = lane >> 4, l15 = lane & 15;
  const f32x4 z4 = {0.f, 0.f, 0.f, 0.f};
  f32x4 acc[4] = {z4, z4, z4, z4};

  const int ra = tid >> 2, ha = (tid & 3) * 8;          // 64 rows, 8 shorts each
  for (int k0 = 0; k0 < 128; k0 += 32) {
    *reinterpret_cast<bf8*>(&Ah[ra * 40 + ha]) =
        *reinterpret_cast<const bf8*>(&Ag[(size_t)(m0 + ra) * 128 + k0 + ha]);
    *reinterpret_cast<bf8*>(&Bh[ra * 40 + ha]) =
        *reinterpret_cast<const bf8*>(&Bg[(size_t)(n0 + ra) * 128 + k0 + ha]);
    __syncthreads();
    bf8 af = *reinterpret_cast<const bf8*>(&Ah[(wave * 16 + l15) * 40 + quad * 8]);
    bf8 bfh[4];
#pragma unroll
    for (int nt = 0; nt < 4; ++nt)
      bfh[nt] = *reinterpret_cast<const bf8*>(&Bh[(nt * 16 + l15) * 40 + quad * 8]);
#pragma unroll
    for (int nt = 0; nt < 4; ++nt)
      acc[nt] = __builtin_amdgcn_mfma_f32_16x16x32_bf16(af, bfh[nt], acc[nt], 0, 0, 0);
    __syncthreads();
  }
#pragma unroll
  for (int nt = 0; nt < 4; ++nt) {
    int col = n0 + nt * 16 + l15;
    float bv = bias[col];
    int rbase = m0 + wave * 16 + quad * 4;
#pragma unroll
    for (int r = 0; r < 4; ++r) {
      float v = acc[nt][r] + bv;
      if (ACT == 1) v = 0.5f * v * (1.f + erff(v * 0.7071067811865476f));
      if (SPLIT) Cb[(size_t)(rbase + r) * N + col] = (unsigned short)f2bf(v);
      else       C[(size_t)(rbase + r) * N + col] = v;
    }
  }
}

// == bf16 MFMA GEMM + residual + LN v3: tile 16(M) x 128(N), grid M/16 ==
// 4 waves each own 32 cols (2 n-tiles); LN row-sums combined via LDS partials.
// out = LN(A.B^T+bias+res)*g+b; FINAL=1: y = LN2(out)*g2+b2 -> bf16 only.
template <int K, int FINAL>
__global__ __launch_bounds__(256) void mgemm_ln3(
    const unsigned short* __restrict__ Ag, const unsigned short* __restrict__ Bg,
    const float* __restrict__ bias, const float* __restrict__ res,
    const float* __restrict__ g, const float* __restrict__ bb,
    const float* __restrict__ g2, const float* __restrict__ bb2,
    float* __restrict__ C, unsigned short* __restrict__ Cb) {
  __shared__ short Ah[16 * 40], Bh[128 * 40];
  __shared__ float red1[16][4], red2[16][4], red3[16][4], red4[16][4];
  const int tid = threadIdx.x;
  const int m0 = blockIdx.x * 16;
  const int wave = tid >> 6, lane = tid & 63, quad = lane >> 4, l15 = lane & 15;
  const f32x4 z4 = {0.f, 0.f, 0.f, 0.f};
  f32x4 acc[2] = {z4, z4};

  const int rb = tid >> 1, hb = (tid & 1) * 16;         // B: 128 rows, 16 shorts each
  for (int k0 = 0; k0 < K; k0 += 32) {
    if (tid < 64) {
      const int ra = tid >> 2, ha = (tid & 3) * 8;
      *reinterpret_cast<bf8*>(&Ah[ra * 40 + ha]) =
          *reinterpret_cast<const bf8*>(&Ag[(size_t)(m0 + ra) * K + k0 + ha]);
    }
    {
      const size_t bbase = (size_t)rb * K + k0 + hb;
      *reinterpret_cast<bf8*>(&Bh[rb * 40 + hb])     = *reinterpret_cast<const bf8*>(&Bg[bbase]);
      *reinterpret_cast<bf8*>(&Bh[rb * 40 + hb + 8]) = *reinterpret_cast<const bf8*>(&Bg[bbase + 8]);
    }
    __syncthreads();
    bf8 af = *reinterpret_cast<const bf8*>(&Ah[l15 * 40 + quad * 8]);
#pragma unroll
    for (int j = 0; j < 2; ++j) {
      bf8 bf = *reinterpret_cast<const bf8*>(&Bh[(wave * 32 + j * 16 + l15) * 40 + quad * 8]);
      acc[j] = __builtin_amdgcn_mfma_f32_16x16x32_bf16(af, bf, acc[j], 0, 0, 0);
    }
    __syncthreads();
  }
  float bias_v[2], g_v[2], bb_v[2], g2_v[2], bb2_v[2];
#pragma unroll
  for (int j = 0; j < 2; ++j) {
    const int col = wave * 32 + j * 16 + l15;
    bias_v[j] = bias[col]; g_v[j] = g[col]; bb_v[j] = bb[col];
    if (FINAL) { g2_v[j] = g2[col]; bb2_v[j] = bb2[col]; }
  }
  float ov[4][2];
#pragma unroll
  for (int r = 0; r < 4; ++r) {
    const int row = m0 + quad * 4 + r;
#pragma unroll
    for (int j = 0; j < 2; ++j)
      ov[r][j] = acc[j][r] + bias_v[j] +
                 res[(size_t)row * 128 + wave * 32 + j * 16 + l15];
    float s = ov[r][0] + ov[r][1];
    s += __shfl_xor(s, 1); s += __shfl_xor(s, 2);
    s += __shfl_xor(s, 4); s += __shfl_xor(s, 8);
    if (l15 == 0) red1[quad * 4 + r][wave] = s;
  }
  __syncthreads();
  float mean[4];
#pragma unroll
  for (int r = 0; r < 4; ++r) {
    const int lr = quad * 4 + r;
    mean[r] = (red1[lr][0] + red1[lr][1] + red1[lr][2] + red1[lr][3]) * 0.0078125f;
  }
#pragma unroll
  for (int r = 0; r < 4; ++r) {
    float s2 = 0.f;
#pragma unroll
    for (int j = 0; j < 2; ++j) { ov[r][j] -= mean[r]; s2 += ov[r][j] * ov[r][j]; }
    s2 += __shfl_xor(s2, 1); s2 += __shfl_xor(s2, 2);
    s2 += __shfl_xor(s2, 4); s2 += __shfl_xor(s2, 8);
    if (l15 == 0) red2[quad * 4 + r][wave] = s2;
  }
  __syncthreads();
  float rstd[4];
#pragma unroll
  for (int r = 0; r < 4; ++r) {
    const int lr = quad * 4 + r;
    rstd[r] = rsqrtf((red2[lr][0] + red2[lr][1] + red2[lr][2] + red2[lr][3]) *
                     0.0078125f + 1e-5f);
  }
  if (FINAL) {
    float yv[4][2];
#pragma unroll
    for (int r = 0; r < 4; ++r) {
      float s3 = 0.f;
#pragma unroll
      for (int j = 0; j < 2; ++j) {
        yv[r][j] = ov[r][j] * rstd[r] * g_v[j] + bb_v[j];
        s3 += yv[r][j];
      }
      s3 += __shfl_xor(s3, 1); s3 += __shfl_xor(s3, 2);
      s3 += __shfl_xor(s3, 4); s3 += __shfl_xor(s3, 8);
      if (l15 == 0) red3[quad * 4 + r][wave] = s3;
    }
    __syncthreads();
    float mean2[4];
#pragma unroll
    for (int r = 0; r < 4; ++r) {
      const int lr = quad * 4 + r;
      mean2[r] = (red3[lr][0] + red3[lr][1] + red3[lr][2] + red3[lr][3]) * 0.0078125f;
    }
#pragma unroll
    for (int r = 0; r < 4; ++r) {
      float s4 = 0.f;
#pragma unroll
      for (int j = 0; j < 2; ++j) { yv[r][j] -= mean2[r]; s4 += yv[r][j] * yv[r][j]; }
      s4 += __shfl_xor(s4, 1); s4 += __shfl_xor(s4, 2);
      s4 += __shfl_xor(s4, 4); s4 += __shfl_xor(s4, 8);
      if (l15 == 0) red4[quad * 4 + r][wave] = s4;
    }
    __syncthreads();
#pragma unroll
    for (int r = 0; r < 4; ++r) {
      const int lr = quad * 4 + r;
      float rstd2 = rsqrtf((red4[lr][0] + red4[lr][1] + red4[lr][2] + red4[lr][3]) *
                           0.0078125f + 1e-5f);
      const int row = m0 + lr;
#pragma unroll
      for (int j = 0; j < 2; ++j) {
        float v = yv[r][j] * rstd2 * g2_v[j] + bb2_v[j];
        Cb[(size_t)row * 128 + wave * 32 + j * 16 + l15] = (unsigned short)f2bf(v);
      }
    }
  } else {
#pragma unroll
    for (int r = 0; r < 4; ++r) {
      const int row = m0 + quad * 4 + r;
#pragma unroll
      for (int j = 0; j < 2; ++j) {
        float v = ov[r][j] * rstd[r] * g_v[j] + bb_v[j];
        size_t off = (size_t)row * 128 + wave * 32 + j * 16 + l15;
        C[off] = v;
        Cb[off] = (unsigned short)f2bf(v);
      }
    }
  }
}

// ====== plain-bf16 MFMA flash attention: block per (qt,h,b) ======
__global__ __launch_bounds__(256) void attn_b(
    const unsigned short* __restrict__ qb, unsigned short* __restrict__ ob) {
  const int qt = blockIdx.x, h = blockIdx.y, b = blockIdx.z;
  __shared__ short Kh[64 * 40];          // [key][d]
  __shared__ short Vth[32 * 72];         // [d][key]
  __shared__ float Ss[64 * 72];
  __shared__ float ms[64], ls[64], alphas[64];
  const int tid = threadIdx.x;
  const int wave = tid >> 6, lane = tid & 63, quad = lane >> 4, l15 = lane & 15;
  const size_t tbase = (size_t)b * 512 + qt * 64;
  bf8 qf;
  {
    const size_t qoff = (tbase + wave * 16 + l15) * 384 + h * 32 + quad * 8;
    qf = *reinterpret_cast<const bf8*>(&qb[qoff]);
  }
  if (tid < 64) { ms[tid] = -1e30f; ls[tid] = 0.f; }
  const f32x4 z4 = {0.f, 0.f, 0.f, 0.f};
  f32x4 o[2] = {z4, z4};
  const float scale = 0.17677669529663687f;  // 1/sqrt(32)
  const int sr = tid >> 2, sc8 = (tid & 3) * 8;
  for (int kt = 0; kt <= qt; ++kt) {
    const size_t kbase = (size_t)b * 512 + kt * 64;
    {
      const size_t koff = (kbase + sr) * 384 + 128 + h * 32 + sc8;
      *reinterpret_cast<bf8*>(&Kh[sr * 40 + sc8]) = *reinterpret_cast<const bf8*>(&qb[koff]);
      const size_t voff = (kbase + sr) * 384 + 256 + h * 32 + sc8;
      bf8 vh8 = *reinterpret_cast<const bf8*>(&qb[voff]);
#pragma unroll
      for (int j = 0; j < 8; ++j) Vth[(sc8 + j) * 72 + sr] = vh8[j];
    }
    __syncthreads();
    {
#pragma unroll
      for (int nt = 0; nt < 4; ++nt) {
        bf8 kf = *reinterpret_cast<const bf8*>(&Kh[(nt * 16 + l15) * 40 + quad * 8]);
        f32x4 s = __builtin_amdgcn_mfma_f32_16x16x32_bf16(qf, kf, z4, 0, 0, 0);
#pragma unroll
        for (int r = 0; r < 4; ++r) {
          int row64 = wave * 16 + quad * 4 + r;
          int col64 = nt * 16 + l15;
          float v = s[r] * scale;
          if (kt == qt && col64 > row64) v += -1e9f;
          Ss[row64 * 72 + col64] = v;
        }
      }
    }
    __syncthreads();
    {
      const int i = tid >> 2, q = tid & 3;
      float mx = -3.4e38f;
      float4 pv[4];
#pragma unroll
      for (int t = 0; t < 4; ++t) {
        pv[t] = *reinterpret_cast<const float4*>(&Ss[i * 72 + q * 16 + t * 4]);
        mx = fmaxf(mx, fmaxf(fmaxf(pv[t].x, pv[t].y), fmaxf(pv[t].z, pv[t].w)));
      }
      mx = fmaxf(mx, __shfl_xor(mx, 1));
      mx = fmaxf(mx, __shfl_xor(mx, 2));
      float mold = ms[i];
      mx = fmaxf(mx, mold);
      float sum = 0.f;
#pragma unroll
      for (int t = 0; t < 4; ++t) {
        pv[t].x = __expf(pv[t].x - mx); pv[t].y = __expf(pv[t].y - mx);
        pv[t].z = __expf(pv[t].z - mx); pv[t].w = __expf(pv[t].w - mx);
        sum += pv[t].x + pv[t].y + pv[t].z + pv[t].w;
        *reinterpret_cast<float4*>(&Ss[i * 72 + q * 16 + t * 4]) = pv[t];
      }
      sum += __shfl_xor(sum, 1);
      sum += __shfl_xor(sum, 2);
      if (q == 0) {
        float alpha = __expf(mold - mx);
        ls[i] = ls[i] * alpha + sum;
        ms[i] = mx;
        alphas[i] = alpha;
      }
    }
    __syncthreads();
    {
      bf8 ph[2];
#pragma unroll
      for (int c = 0; c < 2; ++c) {
        const float* pp = &Ss[(wave * 16 + l15) * 72 + c * 32 + quad * 8];
        float4 p0 = *reinterpret_cast<const float4*>(pp);
        float4 p1 = *reinterpret_cast<const float4*>(pp + 4);
        float pf[8] = {p0.x, p0.y, p0.z, p0.w, p1.x, p1.y, p1.z, p1.w};
#pragma unroll
        for (int j = 0; j < 8; ++j) ph[c][j] = f2bf(pf[j]);
      }
      float a0 = alphas[wave * 16 + quad * 4 + 0];
      float a1 = alphas[wave * 16 + quad * 4 + 1];
      float a2 = alphas[wave * 16 + quad * 4 + 2];
      float a3 = alphas[wave * 16 + quad * 4 + 3];
#pragma unroll
      for (int dt = 0; dt < 2; ++dt) {
        o[dt][0] *= a0; o[dt][1] *= a1; o[dt][2] *= a2; o[dt][3] *= a3;
#pragma unroll
        for (int c = 0; c < 2; ++c) {
          bf8 vf = *reinterpret_cast<const bf8*>(&Vth[(dt * 16 + l15) * 72 + c * 32 + quad * 8]);
          o[dt] = __builtin_amdgcn_mfma_f32_16x16x32_bf16(ph[c], vf, o[dt], 0, 0, 0);
        }
      }
    }
    __syncthreads();
  }
#pragma unroll
  for (int r = 0; r < 4; ++r) {
    float inv = 1.f / ls[wave * 16 + quad * 4 + r];
    size_t row = tbase + wave * 16 + quad * 4 + r;
#pragma unroll
    for (int dt = 0; dt < 2; ++dt) {
      float v = o[dt][r] * inv;
      ob[row * 128 + h * 32 + dt * 16 + l15] = (unsigned short)f2bf(v);
    }
  }
}

__global__ __launch_bounds__(256) void loss_finalize2(const float* __restrict__ lp,
                                                      float* __restrict__ out) {
  float s = 0.f;
  for (int i = threadIdx.x; i < 2048; i += 256) s += lp[i];
#pragma unroll
  for (int o = 1; o < 64; o <<= 1) s += __shfl_xor(s, o);
  __shared__ float red[4];
  if ((threadIdx.x & 63) == 0) red[threadIdx.x >> 6] = s;
  __syncthreads();
  if (threadIdx.x == 0)
    out[0] = 1.25f * (red[0] + red[1] + red[2] + red[3]) / 2097152.0f;
}

extern "C" void kernel_launch(void* const* d_in, const int* in_sizes, int n_in,
                              void* d_out, int out_size, void* d_ws, size_t ws_size,
                              hipStream_t stream) {
  const float* x      = (const float*)d_in[0];
  const float* enc_w1 = (const float*)d_in[1];
  const float* enc_b1 = (const float*)d_in[2];
  const float* enc_w2 = (const float*)d_in[3];
  const float* enc_b2 = (const float*)d_in[4];
  const float* enc_w3 = (const float*)d_in[5];
  const float* enc_b3 = (const float*)d_in[6];
  const float* res_w1 = (const float*)d_in[7];
  const float* res_b1 = (const float*)d_in[8];
  const float* res_w2 = (const float*)d_in[9];
  const float* res_b2 = (const float*)d_in[10];
  const float* pre_w  = (const float*)d_in[11];
  const float* pre_b  = (const float*)d_in[12];
  const float* codebook = (const float*)d_in[13];
  const float* pos_emb  = (const float*)d_in[14];
  const float* qkv_w  = (const float*)d_in[15];
  const float* qkv_b  = (const float*)d_in[16];
  const float* proj_w = (const float*)d_in[17];
  const float* proj_b = (const float*)d_in[18];
  const float* ln1_g  = (const float*)d_in[19];
  const float* ln1_b  = (const float*)d_in[20];
  const float* ln2_g  = (const float*)d_in[21];
  const float* ln2_b  = (const float*)d_in[22];
  const float* ffn_w1 = (const float*)d_in[23];
  const float* ffn_b1 = (const float*)d_in[24];
  const float* ffn_w2 = (const float*)d_in[25];
  const float* ffn_b2 = (const float*)d_in[26];
  const float* fin_g  = (const float*)d_in[27];
  const float* fin_b  = (const float*)d_in[28];
  const float* head_w = (const float*)d_in[29];
  const float* head_b = (const float*)d_in[30];

  float* out = (float*)d_out;
  float* ws  = (float*)d_ws;

  // ws: keys(32768f) | lpart(2048) | pad | wb plane | hhln_b plane
  unsigned long long* keys = (unsigned long long*)ws;
  float* lpart = ws + 32768;
  unsigned short* wb = (unsigned short*)(ws + 36864);        // 589824 ushorts
  unsigned short* hhln_b = (unsigned short*)(ws + 692224);   // 2097152 ushorts

  // d_out scratch overlay (float offsets; dead before head GEMM)
  float* zf = out;                                            // [0 .. 2^21)
  float* hh = out + 2097152;                                  // [2^21 .. 2^22)
  unsigned short* hh_b   = (unsigned short*)(out + 4194304);  // 2M ushorts
  unsigned short* qkvb_b = (unsigned short*)(out + 6291456);  // 6.29M ushorts
  unsigned short* oatt_b = (unsigned short*)(out + 12582912); // 2M ushorts
  unsigned short* fbuf_b = (unsigned short*)(out + 0);        // overlays zf (dead)

  // encoder weight planes overlay qkvb region (dead until first mgemm_b64)
  unsigned short* ewh = (unsigned short*)(out + 6291456);
  unsigned short* ewl = ewh + EWTOT;                          // ends < out+6330368

  // z planes (dead after vq_argmin3, before qkv writes qkvb region)
  unsigned short* zh = (unsigned short*)(out + 6340608);
  unsigned short* zl = (unsigned short*)(out + 7389184);
  // codebook planes + |c|^2 (overlay oatt region, dead until attn_b)
  unsigned short* cbh = (unsigned short*)(out + 12582912);
  unsigned short* cbl = (unsigned short*)(out + 12648448);
  float* cnbuf = out + 12713984;

  const int W_QKV = 0, W_PROJ = 196608, W_F1 = 262144, W_F2 = 393216, W_HEAD = 524288;

  hipMemsetAsync(keys, 0xFF, NPATCH * sizeof(unsigned long long), stream);

  enc_split<<<152, 256, 0, stream>>>(enc_w2, enc_w3, res_w1, res_w2, pre_w, ewh, ewl);
  cb_split<<<512, 256, 0, stream>>>(codebook, cbh, cbl, cnbuf);
  encoder7<<<2048, 256, 0, stream>>>(x, enc_w1, enc_b1, enc_b2, enc_b3,
                                     res_b1, res_b2, pre_b, ewh, ewl, zf, zh, zl);
  cast_w<<<2304, 256, 0, stream>>>(qkv_w, proj_w, ffn_w1, ffn_w2, head_w, wb);
  vq_argmin3<<<dim3(16, 128), 256, 0, stream>>>(zh, zl, cbh, cbl, codebook, keys);
  vq_gather3<<<2048, 256, 0, stream>>>(zf, codebook, pos_emb, keys, hh, hh_b,
                                       lpart, out + IDX_OFF);
  for (int i = 0; i < 4; ++i) {
    mgemm_b64<0, 1><<<dim3(6, 256), 256, 0, stream>>>(
        hh_b, wb + W_QKV + i * 49152, qkv_b + i * 384, nullptr, qkvb_b, 384);
    attn_b<<<dim3(8, 4, 32), 256, 0, stream>>>(qkvb_b, oatt_b);
    mgemm_ln3<128, 0><<<1024, 256, 0, stream>>>(
        oatt_b, wb + W_PROJ + i * 16384, proj_b + i * 128, hh,
        ln1_g + i * 128, ln1_b + i * 128, nullptr, nullptr, hh, hh_b);
    mgemm_b64<1, 1><<<dim3(4, 256), 256, 0, stream>>>(
        hh_b, wb + W_F1 + i * 32768, ffn_b1 + i * 256, nullptr, fbuf_b, 256);
    if (i < 3) {
      mgemm_ln3<256, 0><<<1024, 256, 0, stream>>>(
          fbuf_b, wb + W_F2 + i * 32768, ffn_b2 + i * 128, hh,
          ln2_g + i * 128, ln2_b + i * 128, nullptr, nullptr, hh, hh_b);
    } else {
      mgemm_ln3<256, 1><<<1024, 256, 0, stream>>>(
          fbuf_b, wb + W_F2 + i * 32768, ffn_b2 + i * 128, hh,
          ln2_g + i * 128, ln2_b + i * 128, fin_g, fin_b, hh, hhln_b);
    }
  }
  mgemm_b64<0, 0><<<dim3(16, 256), 256, 0, stream>>>(
      hhln_b, wb + W_HEAD, head_b, out, nullptr, 1024);
  loss_finalize2<<<1, 256, 0, stream>>>(lpart, out + LOSS_OFF);
}